// Round 10
// baseline (20.061 us; speedup 1.0000x reference)
//
#include <hip/hip_runtime.h>
#include <math.h>

namespace {
constexpr int K_ = 9;
constexpr int H_ = 5;
constexpr int NSHELL_ = 321;   // H*(K-1)^2 + 1
constexpr int NPTS_ = 200000;
constexpr int B_ = 512;
constexpr float C_COEF_ = 0.49996397161691486f;
constexpr float LAM0_ = 1.0f;
constexpr float EPS_ = 1e-8f;
constexpr float HLOGK_ = 10.986122886681098f;  // H*ln(K)
constexpr float M_F = 59049.0f;                // K^H
constexpr int NV4_ = NPTS_ / 4;                // 50000 float4s per array
constexpr int NROWB_ = B_ / 8;                 // 64 row blocks (8 waves each)
constexpr int NCOPYB_ = (NV4_ + 511) / 512;    // 98 copy blocks
constexpr int NBLK_ = NROWB_ + NCOPYB_ + 1;    // 163 total (+1 loss) — <= 256 CUs
}

// Single kernel, 512-thread blocks, three roles, PROVABLY DISJOINT write sets:
//  - row blocks  [0, NROWB_):        one batch row per wave (8/block); write
//    lam_new/rho_new at idx-set positions (last-occurrence winner, derived
//    only from the immutable idx input).
//  - copy blocks [NROWB_, +NCOPYB_): copy base lam/rho, skipping idx-set
//    elements (per-block LDS bitmap over 2048 elements; 1 check/thread).
//  - loss block  (last):             1 row/thread, recomputes lam_b*nll (only
//    log-softmax + z-product + rho needed) and tree-reduces into out[0].
// Exactly one writer per out element -> no ordering requirements, no global
// atomics, bit-stable across graph replays.
__global__ __launch_bounds__(512) void fused(const float* __restrict__ logits,
                                             const int* __restrict__ idx,
                                             const int* __restrict__ Y,
                                             const float* __restrict__ lam,
                                             const float* __restrict__ rho,
                                             float* __restrict__ out) {
    const int bid = blockIdx.x;

    if (bid == NROWB_ + NCOPYB_) {
        // ---------------- loss role (512 threads, 1 row each) ----------------
        __shared__ float sz[K_];               // z values (NOT log)
        __shared__ float red[512];
        const int t = threadIdx.x;
        if (t < K_) {
            float z = 0.f;
            for (int j = 0; j < K_; ++j) {
                float d = (float)(t - j);
                z += __expf(-C_COEF_ * d * d);
            }
            sz[t] = z;
        }
        __syncthreads();
        const int b = t;
        const int id = idx[b];
        float sumxy = 0.f, summ = 0.f, prodse = 1.f, prodz = 1.f;
        #pragma unroll
        for (int h = 0; h < H_; ++h) {
            const int yh = Y[id * H_ + h];
            const float* lg = logits + (b * H_ + h) * K_;
            float x[K_];
            float m = -1e30f;
            #pragma unroll
            for (int k = 0; k < K_; ++k) { x[k] = lg[k]; m = fmaxf(m, x[k]); }
            float se = 0.f;
            #pragma unroll
            for (int k = 0; k < K_; ++k) se += __expf(x[k] - m);
            sumxy += x[yh];
            summ  += m;
            prodse *= se;                      // <= 9^5, safe in fp32
            prodz  *= sz[yh];
        }
        const float logp_t = sumxy - summ - __logf(prodse);
        const float A = M_F / prodz;           // Kpi_t = M / Z_mode
        const float rho_b = rho[id];
        const float S_t = 1.f + rho_b * (A - 1.f);
        const float nll = -(logp_t + __logf(S_t + EPS_));
        red[t] = lam[id] * nll;
        __syncthreads();
        for (int s = 256; s > 0; s >>= 1) {
            if (t < s) red[t] += red[t + s];
            __syncthreads();
        }
        if (t == 0) out[0] = red[0] * (1.f / 512.f);
        return;
    }

    if (bid >= NROWB_) {
        // ---------------- copy role ----------------
        __shared__ unsigned bm[64];            // 2048-bit hit bitmap for this block's range
        const int cb = bid - NROWB_;
        const int l  = threadIdx.x;            // local float4 index
        const int i  = cb * 512 + l;           // global float4 index
        const int ebase = cb * 2048;           // first element covered by this block
        if (l < 64) bm[l] = 0u;
        __syncthreads();
        {
            int v = idx[l];                    // exactly one idx check per thread
            unsigned rel = (unsigned)(v - ebase);
            if (rel < 2048u) atomicOr(&bm[rel >> 5], 1u << (rel & 31));
        }
        __syncthreads();
        if (i < NV4_) {
            unsigned m = (bm[l >> 3] >> ((4 * l) & 31)) & 0xFu;
            float4 l4 = ((const float4*)lam)[i];
            float4 r4 = ((const float4*)rho)[i];
            int o  = 1 + 4 * i;
            int o2 = o + NPTS_;
            if (m == 0u) {  // common path: unconditional stores (mergeable)
                out[o]      = l4.x; out[o + 1]  = l4.y; out[o + 2]  = l4.z; out[o + 3]  = l4.w;
                out[o2]     = r4.x; out[o2 + 1] = r4.y; out[o2 + 2] = r4.z; out[o2 + 3] = r4.w;
            } else {        // rare: skip elements owned by row blocks
                if (!(m & 1u)) { out[o]     = l4.x; out[o2]     = r4.x; }
                if (!(m & 2u)) { out[o + 1] = l4.y; out[o2 + 1] = r4.y; }
                if (!(m & 4u)) { out[o + 2] = l4.z; out[o2 + 2] = r4.z; }
                if (!(m & 8u)) { out[o + 3] = l4.w; out[o2 + 3] = r4.w; }
            }
        }
        return;
    }

    // ---------------- row role (8 waves, one row each) ----------------
    __shared__ float logp[8][H_][K_];
    __shared__ float p[8][H_][K_];
    __shared__ float zt[8][K_];                // z values (NOT log)
    __shared__ int   ysh[8][H_];
    __shared__ float acc[8][2][NSHELL_];

    const int wid  = threadIdx.x >> 6;
    const int lane = threadIdx.x & 63;
    const int b    = bid * 8 + wid;
    const int id   = idx[b];

    if (lane < H_) ysh[wid][lane] = Y[id * H_ + lane];
    if (lane < K_) {
        float z = 0.f;
        for (int j = 0; j < K_; ++j) {
            float d = (float)(lane - j);
            z += __expf(-C_COEF_ * d * d);
        }
        zt[wid][lane] = z;
    }
    for (int s = lane; s < NSHELL_; s += 64) acc[wid][0][s] = 0.f;
    if (lane < H_) {
        // log_softmax for factor h = lane
        const float* lg = logits + (b * H_ + lane) * K_;
        float x[K_];
        float m = -1e30f;
        for (int k = 0; k < K_; ++k) { x[k] = lg[k]; m = fmaxf(m, x[k]); }
        float se = 0.f;
        for (int k = 0; k < K_; ++k) se += __expf(x[k] - m);
        float ls = m + __logf(se);
        for (int k = 0; k < K_; ++k) {
            float lp = x[k] - ls;
            logp[wid][lane][k] = lp;
            p[wid][lane][k] = __expf(lp);
        }
    }

    // last-occurrence test: does any pos > b share our idx value?
    bool later_dup = false;
    for (int j = 0; j < 8; ++j) {
        int pos = j * 64 + lane;
        int v = idx[pos];
        later_dup |= (pos > b) && (v == id);
    }
    const bool keep = (__any(later_dup ? 1 : 0) == 0);

    __syncthreads();

    // init convolution with factor h=0 (single-lane scatter, <=9 entries)
    if (lane == 0) {
        int y0 = ysh[wid][0];
        for (int c = 0; c < K_; ++c) {
            int o = c - y0; o *= o;
            acc[wid][0][o] += p[wid][0][c];
        }
    }
    __syncthreads();

    // convolve factors h=1..4 (gather form: no conflicts, no atomics)
    int cur = 0;
    #pragma unroll
    for (int h = 1; h < H_; ++h) {
        const int yh = ysh[wid][h];
        float w[K_];
        int off[K_];
        #pragma unroll
        for (int c = 0; c < K_; ++c) { int o = c - yh; off[c] = o * o; w[c] = p[wid][h][c]; }
        #pragma unroll
        for (int j = 0; j < 6; ++j) {
            int s = lane + 64 * j;
            if (s < NSHELL_) {
                float v = 0.f;
                #pragma unroll
                for (int c = 0; c < K_; ++c) {
                    int sp = s - off[c];
                    if (sp >= 0) v += w[c] * acc[wid][cur][sp];
                }
                acc[wid][cur ^ 1][s] = v;
            }
        }
        cur ^= 1;
        __syncthreads();
    }

    // per-row scalars
    float prodz = 1.f, logp_t = 0.f;
    #pragma unroll
    for (int h = 0; h < H_; ++h) {
        int yh = ysh[wid][h];
        prodz  *= zt[wid][yh];
        logp_t += logp[wid][h][yh];
    }
    const float A = M_F / prodz;  // Kpi_t = M / Z_mode
    const float rho_b = rho[id];
    const float lam_b = lam[id];

    // shell sums — rho_b is wave-uniform, compute only the branch we need.
    // ratio = -expm1(-log1p(x))/srho == (Kpi-1)/(1+x), x=srho*(Kpi-1) (exact).
    // Kpi iterated: Kpi(s+64) = Kpi(s) * exp(-64C).
    const float kstep = __expf(-64.f * C_COEF_);
    float Kpi = A * __expf(-C_COEF_ * (float)lane);
    float d0, d1;
    if (rho_b == 0.f) {
        float k1 = 0.f, k2 = 0.f;
        #pragma unroll
        for (int j = 0; j < 6; ++j) {
            int s = lane + 64 * j;
            if (s < NSHELL_) {
                float ps = acc[wid][cur][s];
                k1 = fmaf(ps, Kpi, k1);
                k2 = fmaf(ps * Kpi, Kpi, k2);
            }
            Kpi *= kstep;
        }
        for (int o = 32; o > 0; o >>= 1) {
            k1 += __shfl_down(k1, o);
            k2 += __shfl_down(k2, o);
        }
        d0 = k1 - 1.f;
        d1 = k2 - 2.f * k1 + 1.f;
    } else {
        float dr1 = 0.f, dr2 = 0.f;
        #pragma unroll
        for (int j = 0; j < 6; ++j) {
            int s = lane + 64 * j;
            if (s < NSHELL_) {
                float ps = acc[wid][cur][s];
                float km1 = Kpi - 1.f;
                float ratio = km1 / fmaf(rho_b, km1, 1.f);
                dr1 = fmaf(ps, ratio, dr1);
                dr2 = fmaf(ps * ratio, ratio, dr2);
            }
            Kpi *= kstep;
        }
        for (int o = 32; o > 0; o >>= 1) {
            dr1 += __shfl_down(dr1, o);
            dr2 += __shfl_down(dr2, o);
        }
        d0 = dr1;
        d1 = dr2;
    }

    if (lane == 0 && keep) {
        float S_t = 1.f + rho_b * (A - 1.f);
        float nll = -(logp_t + __logf(S_t + EPS_));
        float rho_new = rho_b - d0 / (d1 + EPS_);
        rho_new = fminf(fmaxf(rho_new, 0.f), 1.f);
        float lam_tgt = LAM0_ * HLOGK_ / (nll + EPS_);
        float lam_new = 0.9f * lam_b + 0.1f * fminf(lam_tgt, LAM0_);
        lam_new = fminf(fmaxf(lam_new, LAM0_ * 0.5f), LAM0_);
        out[1 + id]         = lam_new;
        out[1 + NPTS_ + id] = rho_new;
    }
}

extern "C" void kernel_launch(void* const* d_in, const int* in_sizes, int n_in,
                              void* d_out, int out_size, void* d_ws, size_t ws_size,
                              hipStream_t stream) {
    const float* logits = (const float*)d_in[0];  // (B, H, K) fp32
    const int*   idx    = (const int*)d_in[1];    // (B,)
    const int*   Y      = (const int*)d_in[2];    // (N, H)
    const float* lam    = (const float*)d_in[3];  // (N,)
    const float* rho    = (const float*)d_in[4];  // (N,)
    float* out = (float*)d_out;                   // [loss | lam_new(N) | rho_new(N)]

    fused<<<NBLK_, 512, 0, stream>>>(logits, idx, Y, lam, rho, out);
}

// Round 11
// 19.425 us; speedup vs baseline: 1.0327x; 1.0327x over previous
//
#include <hip/hip_runtime.h>
#include <math.h>

namespace {
constexpr int K_ = 9;
constexpr int H_ = 5;
constexpr int NSHELL_ = 321;   // H*(K-1)^2 + 1
constexpr int NPTS_ = 200000;
constexpr int B_ = 512;
constexpr float C_COEF_ = 0.49996397161691486f;
constexpr float LAM0_ = 1.0f;
constexpr float EPS_ = 1e-8f;
constexpr float HLOGK_ = 10.986122886681098f;  // H*ln(K)
constexpr float M_F = 59049.0f;                // K^H
constexpr int NV4_ = NPTS_ / 4;                // 50000 float4s per array
constexpr int NCOPY_ = (NV4_ + 255) / 256;     // 196 copy blocks
constexpr int NROW_ = B_ / 4;                  // 128 row blocks (4 waves each)
constexpr int NBLK_ = NROW_ + NCOPY_ + 1;      // + 1 loss block
}

// R9 configuration (best measured: 19.45 us). Single kernel, three roles,
// PROVABLY DISJOINT write sets:
//  - row blocks  [0, NROW_):        one batch row per wave; write lam_new /
//    rho_new at out positions in the idx set (last-occurrence winner, derived
//    only from the immutable idx input).
//  - copy blocks [NROW_, +NCOPY_):  copy base lam/rho, SKIPPING idx-set
//    elements (membership via per-block LDS bitmap; 2 checks/thread).
//  - loss block  (last):            recomputes lam_b*nll for all 512 rows
//    (log-softmax + z-product + rho only) and tree-reduces into out[0].
// Exactly one writer per out element -> no inter-block ordering requirement,
// no fences, no global atomics, bit-stable across graph replays.
__global__ __launch_bounds__(256) void fused(const float* __restrict__ logits,
                                             const int* __restrict__ idx,
                                             const int* __restrict__ Y,
                                             const float* __restrict__ lam,
                                             const float* __restrict__ rho,
                                             float* __restrict__ out) {
    const int bid = blockIdx.x;

    if (bid == NROW_ + NCOPY_) {
        // ---------------- loss role ----------------
        __shared__ float sz[K_];               // z values (NOT log)
        __shared__ float red[256];
        const int t = threadIdx.x;
        if (t < K_) {
            float z = 0.f;
            for (int j = 0; j < K_; ++j) {
                float d = (float)(t - j);
                z += __expf(-C_COEF_ * d * d);
            }
            sz[t] = z;
        }
        __syncthreads();
        float v = 0.f;
        #pragma unroll
        for (int r = 0; r < 2; ++r) {
            const int b = t + 256 * r;
            const int id = idx[b];
            float sumxy = 0.f, summ = 0.f, prodse = 1.f, prodz = 1.f;
            #pragma unroll
            for (int h = 0; h < H_; ++h) {
                const int yh = Y[id * H_ + h];
                const float* lg = logits + (b * H_ + h) * K_;
                float x[K_];
                float m = -1e30f;
                #pragma unroll
                for (int k = 0; k < K_; ++k) { x[k] = lg[k]; m = fmaxf(m, x[k]); }
                float se = 0.f;
                #pragma unroll
                for (int k = 0; k < K_; ++k) se += __expf(x[k] - m);
                sumxy += x[yh];
                summ  += m;
                prodse *= se;                  // <= 9^5, safe in fp32
                prodz  *= sz[yh];
            }
            const float logp_t = sumxy - summ - __logf(prodse);
            const float A = M_F / prodz;       // Kpi_t = M / Z_mode
            const float rho_b = rho[id];
            const float S_t = 1.f + rho_b * (A - 1.f);
            const float nll = -(logp_t + __logf(S_t + EPS_));
            v += lam[id] * nll;
        }
        red[t] = v;
        __syncthreads();
        for (int s = 128; s > 0; s >>= 1) {
            if (t < s) red[t] += red[t + s];
            __syncthreads();
        }
        if (t == 0) out[0] = red[0] * (1.f / 512.f);
        return;
    }

    if (bid >= NROW_) {
        // ---------------- copy role ----------------
        __shared__ unsigned bm[32];            // 1024-bit hit bitmap for this block's range
        const int cb = bid - NROW_;
        const int l  = threadIdx.x;            // local float4 index
        const int i  = cb * 256 + l;           // global float4 index
        const int ebase = cb * 1024;           // first element covered by this block
        if (l < 32) bm[l] = 0u;
        __syncthreads();
        #pragma unroll
        for (int t = 0; t < 2; ++t) {
            int v = idx[2 * l + t];
            unsigned rel = (unsigned)(v - ebase);
            if (rel < 1024u) atomicOr(&bm[rel >> 5], 1u << (rel & 31));
        }
        __syncthreads();
        if (i < NV4_) {
            unsigned m = (bm[l >> 3] >> ((4 * l) & 31)) & 0xFu;
            float4 l4 = ((const float4*)lam)[i];
            float4 r4 = ((const float4*)rho)[i];
            int o  = 1 + 4 * i;
            int o2 = o + NPTS_;
            if (m == 0u) {  // common path: unconditional stores (mergeable)
                out[o]      = l4.x; out[o + 1]  = l4.y; out[o + 2]  = l4.z; out[o + 3]  = l4.w;
                out[o2]     = r4.x; out[o2 + 1] = r4.y; out[o2 + 2] = r4.z; out[o2 + 3] = r4.w;
            } else {        // rare: skip elements owned by row blocks
                if (!(m & 1u)) { out[o]     = l4.x; out[o2]     = r4.x; }
                if (!(m & 2u)) { out[o + 1] = l4.y; out[o2 + 1] = r4.y; }
                if (!(m & 4u)) { out[o + 2] = l4.z; out[o2 + 2] = r4.z; }
                if (!(m & 8u)) { out[o + 3] = l4.w; out[o2 + 3] = r4.w; }
            }
        }
        return;
    }

    // ---------------- row role ----------------
    __shared__ float logp[4][H_][K_];
    __shared__ float p[4][H_][K_];
    __shared__ float zt[4][K_];                // z values (NOT log)
    __shared__ int   ysh[4][H_];
    __shared__ float acc[4][2][NSHELL_];

    const int wid  = threadIdx.x >> 6;
    const int lane = threadIdx.x & 63;
    const int b    = bid * 4 + wid;
    const int id   = idx[b];

    if (lane < H_) ysh[wid][lane] = Y[id * H_ + lane];
    if (lane < K_) {
        float z = 0.f;
        for (int j = 0; j < K_; ++j) {
            float d = (float)(lane - j);
            z += __expf(-C_COEF_ * d * d);
        }
        zt[wid][lane] = z;
    }
    for (int s = lane; s < NSHELL_; s += 64) acc[wid][0][s] = 0.f;
    if (lane < H_) {
        // log_softmax for factor h = lane
        const float* lg = logits + (b * H_ + lane) * K_;
        float x[K_];
        float m = -1e30f;
        for (int k = 0; k < K_; ++k) { x[k] = lg[k]; m = fmaxf(m, x[k]); }
        float se = 0.f;
        for (int k = 0; k < K_; ++k) se += __expf(x[k] - m);
        float ls = m + __logf(se);
        for (int k = 0; k < K_; ++k) {
            float lp = x[k] - ls;
            logp[wid][lane][k] = lp;
            p[wid][lane][k] = __expf(lp);
        }
    }

    // last-occurrence test: does any pos > b share our idx value?
    bool later_dup = false;
    for (int j = 0; j < 8; ++j) {
        int pos = j * 64 + lane;
        int v = idx[pos];
        later_dup |= (pos > b) && (v == id);
    }
    const bool keep = (__any(later_dup ? 1 : 0) == 0);

    __syncthreads();

    // init convolution with factor h=0 (single-lane scatter, <=9 entries)
    if (lane == 0) {
        int y0 = ysh[wid][0];
        for (int c = 0; c < K_; ++c) {
            int o = c - y0; o *= o;
            acc[wid][0][o] += p[wid][0][c];
        }
    }
    __syncthreads();

    // convolve factors h=1..4 (gather form: no conflicts, no atomics)
    int cur = 0;
    #pragma unroll
    for (int h = 1; h < H_; ++h) {
        const int yh = ysh[wid][h];
        float w[K_];
        int off[K_];
        #pragma unroll
        for (int c = 0; c < K_; ++c) { int o = c - yh; off[c] = o * o; w[c] = p[wid][h][c]; }
        #pragma unroll
        for (int j = 0; j < 6; ++j) {
            int s = lane + 64 * j;
            if (s < NSHELL_) {
                float v = 0.f;
                #pragma unroll
                for (int c = 0; c < K_; ++c) {
                    int sp = s - off[c];
                    if (sp >= 0) v += w[c] * acc[wid][cur][sp];
                }
                acc[wid][cur ^ 1][s] = v;
            }
        }
        cur ^= 1;
        __syncthreads();
    }

    // per-row scalars
    float prodz = 1.f, logp_t = 0.f;
    #pragma unroll
    for (int h = 0; h < H_; ++h) {
        int yh = ysh[wid][h];
        prodz  *= zt[wid][yh];
        logp_t += logp[wid][h][yh];
    }
    const float A = M_F / prodz;  // Kpi_t = M / Z_mode
    const float rho_b = rho[id];
    const float lam_b = lam[id];
    const float srho = (rho_b == 0.f) ? 1.f : rho_b;

    // shell sums. ratio = -expm1(-log1p(x))/srho == (Kpi-1)/(1+x), x=srho*(Kpi-1)
    // (exact identity). Kpi iterated: Kpi(s+64) = Kpi(s) * exp(-64C).
    const float kstep = __expf(-64.f * C_COEF_);
    float Kpi = A * __expf(-C_COEF_ * (float)lane);
    float k1 = 0.f, k2 = 0.f, dr1 = 0.f, dr2 = 0.f;
    #pragma unroll
    for (int j = 0; j < 6; ++j) {
        int s = lane + 64 * j;
        if (s < NSHELL_) {
            float ps = acc[wid][cur][s];
            float km1 = Kpi - 1.f;
            float ratio = km1 / fmaf(srho, km1, 1.f);
            k1  = fmaf(ps, Kpi, k1);
            k2  = fmaf(ps * Kpi, Kpi, k2);
            dr1 = fmaf(ps, ratio, dr1);
            dr2 = fmaf(ps * ratio, ratio, dr2);
        }
        Kpi *= kstep;
    }
    for (int o = 32; o > 0; o >>= 1) {
        k1  += __shfl_down(k1, o);
        k2  += __shfl_down(k2, o);
        dr1 += __shfl_down(dr1, o);
        dr2 += __shfl_down(dr2, o);
    }

    if (lane == 0 && keep) {
        float d0, d1;
        if (rho_b == 0.f) { d0 = k1 - 1.f; d1 = k2 - 2.f * k1 + 1.f; }
        else              { d0 = dr1;      d1 = dr2; }
        float S_t = 1.f + rho_b * (A - 1.f);
        float nll = -(logp_t + __logf(S_t + EPS_));
        float rho_new = rho_b - d0 / (d1 + EPS_);
        rho_new = fminf(fmaxf(rho_new, 0.f), 1.f);
        float lam_tgt = LAM0_ * HLOGK_ / (nll + EPS_);
        float lam_new = 0.9f * lam_b + 0.1f * fminf(lam_tgt, LAM0_);
        lam_new = fminf(fmaxf(lam_new, LAM0_ * 0.5f), LAM0_);
        out[1 + id]         = lam_new;
        out[1 + NPTS_ + id] = rho_new;
    }
}

extern "C" void kernel_launch(void* const* d_in, const int* in_sizes, int n_in,
                              void* d_out, int out_size, void* d_ws, size_t ws_size,
                              hipStream_t stream) {
    const float* logits = (const float*)d_in[0];  // (B, H, K) fp32
    const int*   idx    = (const int*)d_in[1];    // (B,)
    const int*   Y      = (const int*)d_in[2];    // (N, H)
    const float* lam    = (const float*)d_in[3];  // (N,)
    const float* rho    = (const float*)d_in[4];  // (N,)
    float* out = (float*)d_out;                   // [loss | lam_new(N) | rho_new(N)]

    fused<<<NBLK_, 256, 0, stream>>>(logits, idx, Y, lam, rho, out);
}